// Round 12
// baseline (112.551 us; speedup 1.0000x reference)
//
#include <hip/hip_runtime.h>
#include <hip/hip_bf16.h>

// ContactPredictionHead: logits[b,i,j,o] = sum_d h[b,i,d]*h[b,j,d]*Wp[o,d] + bias[o]
// (diff term antisymmetric -> cancels under symmetrization; prod term symmetric.)
// Batched GEMM: per batch  C[2048 x 4096] = A[2048 x 1280] * Beff^T,
//   Beff[2j+o, d] = h[b,j,d] * Wp[o,d],  row-major C == d_out layout.
// Round 12: R11 schedule kept; inner MFMA switched 16x16x32 -> 32x32x16
// (measured rate 2495 vs 2075 TF => MFMA pipe floor -17%; LDS traffic is
// shape-invariant; MFMA issue-slot count halves -> more ds_read issue room).
// Frags per wave: 4 m-tiles x 2 n-tiles of 32x32, K-tile = 4 ksteps of 16.
// A/B frag: row|col = lane&31, k0 = (lane>>5)*8.  C/D (verified m74/m101):
// col = lane&31, row = (reg&3) + 8*(reg>>2) + 4*(lane>>5).
// Read swizzle folds to byte_off = base ^ (kstep<<5) (chunk bits 4-6 only).

typedef __attribute__((ext_vector_type(8))) short bf16x8;
typedef __attribute__((ext_vector_type(4))) float f32x4;
typedef __attribute__((ext_vector_type(16))) float f32x16;

constexpr int cB = 4, cL = 2048, cD = 1280, cO = 2;
constexpr int NROW = cL * cO;          // 4096
constexpr int BM = 256, BN = 256, BK = 64;
constexpr int KT = cD / BK;            // 20
constexpr int MT2 = cL / BM;           // 8
constexpr int NT2 = NROW / BN;         // 16
constexpr int NTILE = cB * MT2 * NT2;  // 512 output tiles
constexpr int NPBLK = NTILE / 2;       // 256 persistent blocks

__device__ __forceinline__ unsigned short f2bf(float f) {
  unsigned int u = __float_as_uint(f);
  u += 0x7fffu + ((u >> 16) & 1u);
  return (unsigned short)(u >> 16);
}

#define GLOAD_LDS16(g, l)                                           \
  __builtin_amdgcn_global_load_lds(                                 \
      (const __attribute__((address_space(1))) void*)(g),           \
      (__attribute__((address_space(3))) void*)(l), 16, 0, 0)

// ---------------- pack: h -> bf16 A, (h*Wp) -> bf16 Beff ----------------
constexpr int ACH = cB * cL * cD / 8;
constexpr int BCH = cB * 2 * cL * cD / 8;

__global__ __launch_bounds__(256) void cph_pack(
    const float* __restrict__ h, const float* __restrict__ W,
    unsigned short* __restrict__ Apk, unsigned short* __restrict__ Bpk) {
  int idx = blockIdx.x * 256 + threadIdx.x;
  if (idx < ACH) {
    const float* src = h + (size_t)idx * 8;
    float4 x0 = *(const float4*)src;
    float4 x1 = *(const float4*)(src + 4);
    bf16x8 v;
    v[0] = (short)f2bf(x0.x); v[1] = (short)f2bf(x0.y);
    v[2] = (short)f2bf(x0.z); v[3] = (short)f2bf(x0.w);
    v[4] = (short)f2bf(x1.x); v[5] = (short)f2bf(x1.y);
    v[6] = (short)f2bf(x1.z); v[7] = (short)f2bf(x1.w);
    *(bf16x8*)(Apk + (size_t)idx * 8) = v;
  } else {
    idx -= ACH;
    if (idx >= BCH) return;
    int c = idx % (cD / 8);
    int n = (idx / (cD / 8)) % (2 * cL);
    int b = idx / ((cD / 8) * 2 * cL);
    int j = n >> 1, o = n & 1;
    const float* src = h + ((size_t)b * cL + j) * cD + c * 8;
    const float* ws  = W + (size_t)o * (2 * cD) + c * 8;
    float4 x0 = *(const float4*)src;
    float4 x1 = *(const float4*)(src + 4);
    float4 w0 = *(const float4*)ws;
    float4 w1 = *(const float4*)(ws + 4);
    bf16x8 v;
    v[0] = (short)f2bf(x0.x * w0.x); v[1] = (short)f2bf(x0.y * w0.y);
    v[2] = (short)f2bf(x0.z * w0.z); v[3] = (short)f2bf(x0.w * w0.w);
    v[4] = (short)f2bf(x1.x * w1.x); v[5] = (short)f2bf(x1.y * w1.y);
    v[6] = (short)f2bf(x1.z * w1.z); v[7] = (short)f2bf(x1.w * w1.w);
    *(bf16x8*)(Bpk + ((size_t)b * (2 * cL) + n) * cD + c * 8) = v;
  }
}

// ------------- GEMM: 256x256, 8 waves (2M x 4N), 32x32x16 MFMA -------------
__global__ __launch_bounds__(512, 2) void cph_gemm256(
    const unsigned short* __restrict__ Apk, const unsigned short* __restrict__ Bpk,
    const float* __restrict__ bias, float* __restrict__ out) {
  __shared__ __align__(16) char smem[131072];  // [2 buf][A 32K | B 32K]

  int tid  = threadIdx.x;
  int wave = tid >> 6, lane = tid & 63;
  int wm = wave >> 2, wn = wave & 3;   // per-wave C = 128 x 64

  int lr   = lane >> 3;                 // staging row within an 8-row slab
  int gc8  = ((lane & 7) ^ lr) * 8;     // inverse-swizzled global chunk (elems)
  int l31  = lane & 31;
  int kc2  = lane >> 5;                 // k-half within a kstep
  int c0   = kc2 ^ (l31 & 7);           // swizzled 16B-chunk index at kstep 0
  // LDS read byte offsets (per-lane constants; kstep applied as ^(kstep<<5))
  int offA[4], offB[2];
#pragma unroll
  for (int m = 0; m < 4; ++m) offA[m] = wm * 16384 + (m * 32 + l31) * 128 + c0 * 16;
#pragma unroll
  for (int n = 0; n < 2; ++n) offB[n] = 32768 + wn * 8192 + (n * 32 + l31) * 128 + c0 * 16;
  // LDS staging dest offsets (wave-uniform constants)
  int dB0 = 32768 + wave * 2048;
  int dB1 = 49152 + wave * 2048;
  int rA0 = ((wave & 4) << 5) + (wave & 3) * 8;   // A slab base row, stripe 0
  int dA0 = rA0 * 128, dA1 = (rA0 + 32) * 128, dA2 = (rA0 + 64) * 128, dA3 = (rA0 + 96) * 128;

  const unsigned short *pB0a, *pB0b, *pB1a, *pB1b, *pA0, *pA1, *pA2, *pA3;
  auto setPtrs = [&](const unsigned short* Ab, const unsigned short* Bb) {
    pB0a = Bb + (size_t)(wave * 16 + lr) * cD + gc8;
    pB0b = pB0a + 8 * (size_t)cD;
    pB1a = Bb + (size_t)(128 + wave * 16 + lr) * cD + gc8;
    pB1b = pB1a + 8 * (size_t)cD;
    pA0 = Ab + (size_t)(rA0 + lr) * cD + gc8;
    pA1 = pA0 + 32 * (size_t)cD;
    pA2 = pA0 + 64 * (size_t)cD;
    pA3 = pA0 + 96 * (size_t)cD;
  };
  auto stageTile = [&](int buf) {
    int bo = buf << 16;
    GLOAD_LDS16(pB0a, smem + bo + dB0);
    GLOAD_LDS16(pB0b, smem + bo + dB0 + 1024);
    GLOAD_LDS16(pB1a, smem + bo + dB1);
    GLOAD_LDS16(pB1b, smem + bo + dB1 + 1024);
    GLOAD_LDS16(pA0, smem + bo + dA0);
    GLOAD_LDS16(pA1, smem + bo + dA1);
    GLOAD_LDS16(pA2, smem + bo + dA2);
    GLOAD_LDS16(pA3, smem + bo + dA3);
    pB0a += BK; pB0b += BK; pB1a += BK; pB1b += BK;
    pA0 += BK; pA1 += BK; pA2 += BK; pA3 += BK;
  };

  f32x16 acc[4][2];

#define MFMA8(A, B)                                                           \
  _Pragma("unroll")                                                           \
  for (int m_ = 0; m_ < 4; ++m_)                                              \
    _Pragma("unroll")                                                         \
    for (int n_ = 0; n_ < 2; ++n_)                                            \
      acc[m_][n_] = __builtin_amdgcn_mfma_f32_32x32x16_bf16(                  \
          A[m_], B[n_], acc[m_][n_], 0, 0, 0);

  // decode tile 0 and prologue-stage it
  {
    int orig = (int)blockIdx.x;
    int bid  = (orig & 7) * (NTILE / 8) + (orig >> 3);
    int b    = bid / (MT2 * NT2);
    int rem  = bid % (MT2 * NT2);
    setPtrs(Apk + ((size_t)b * cL + (rem / NT2) * BM) * cD,
            Bpk + ((size_t)b * NROW + (rem % NT2) * BN) * cD);
  }
  stageTile(0);

#pragma unroll
  for (int part = 0; part < 2; ++part) {
    int orig = (int)blockIdx.x + part * NPBLK;
    int bid  = (orig & 7) * (NTILE / 8) + (orig >> 3);
    int b    = bid / (MT2 * NT2);
    int rem  = bid % (MT2 * NT2);
    int mt   = rem / NT2, nt = rem % NT2;

    asm volatile("s_waitcnt vmcnt(0)");   // this part's tile 0 landed
    __builtin_amdgcn_s_barrier();

#pragma unroll
    for (int mf = 0; mf < 4; ++mf)
#pragma unroll
      for (int nf = 0; nf < 2; ++nf)
#pragma unroll
        for (int r = 0; r < 16; ++r)
          acc[mf][nf][r] = 0.f;

    for (int t = 0; t < KT; ++t) {
      const int X = t & 1;
      const char* bb = smem + (X << 16);
      bf16x8 A0[4], A1[4], B0[2], B1[2];

      // kstep 0 reads FIRST (critical path), then stage, then pipeline
#pragma unroll
      for (int n = 0; n < 2; ++n) B0[n] = *(const bf16x8*)(bb + offB[n]);
#pragma unroll
      for (int m = 0; m < 4; ++m) A0[m] = *(const bf16x8*)(bb + offA[m]);

      if (t + 1 < KT) {
        stageTile(X ^ 1);
      } else if (part == 0) {
        int orig1 = (int)blockIdx.x + NPBLK;
        int bid1  = (orig1 & 7) * (NTILE / 8) + (orig1 >> 3);
        int b1    = bid1 / (MT2 * NT2);
        int rem1  = bid1 % (MT2 * NT2);
        setPtrs(Apk + ((size_t)b1 * cL + (rem1 / NT2) * BM) * cD,
                Bpk + ((size_t)b1 * NROW + (rem1 % NT2) * BN) * cD);
        stageTile(X ^ 1);
      }

      // kstep 1 reads, MFMA kstep 0
#pragma unroll
      for (int n = 0; n < 2; ++n) B1[n] = *(const bf16x8*)(bb + (offB[n] ^ 32));
#pragma unroll
      for (int m = 0; m < 4; ++m) A1[m] = *(const bf16x8*)(bb + (offA[m] ^ 32));
      MFMA8(A0, B0);

      // kstep 2 reads, MFMA kstep 1
#pragma unroll
      for (int n = 0; n < 2; ++n) B0[n] = *(const bf16x8*)(bb + (offB[n] ^ 64));
#pragma unroll
      for (int m = 0; m < 4; ++m) A0[m] = *(const bf16x8*)(bb + (offA[m] ^ 64));
      MFMA8(A1, B1);

      // kstep 3 reads, MFMA kstep 2
#pragma unroll
      for (int n = 0; n < 2; ++n) B1[n] = *(const bf16x8*)(bb + (offB[n] ^ 96));
#pragma unroll
      for (int m = 0; m < 4; ++m) A1[m] = *(const bf16x8*)(bb + (offA[m] ^ 96));
      MFMA8(A0, B0);

      // vmcnt hoisted: next tile's loads were issued ~a full tile ago
      asm volatile("s_waitcnt vmcnt(0)");
      MFMA8(A1, B1);

      if (t + 1 < KT) __builtin_amdgcn_s_barrier();
    }

    // epilogue: C/D 32x32 layout col = lane&31, row = (reg&3)+8*(reg>>2)+4*(lane>>5)
    int i0 = mt * BM + wm * 128 + (kc2 << 2);
    int n0 = nt * BN + wn * 64 + l31;
    float badd = bias[n0 & 1];
    float* outb = out + (size_t)b * cL * NROW;
#pragma unroll
    for (int mf = 0; mf < 4; ++mf) {
#pragma unroll
      for (int rg = 0; rg < 16; ++rg) {
        int row = (rg & 3) + 8 * (rg >> 2);
        size_t rowoff = (size_t)(i0 + mf * 32 + row) * NROW;
#pragma unroll
        for (int nf = 0; nf < 2; ++nf)
          outb[rowoff + n0 + nf * 32] = acc[mf][nf][rg] + badd;
      }
    }
  }
#undef MFMA8
}

// ---------------- fallback (ws too small): fused 128^2 full-grid GEMM ----------------
constexpr int fBM = 128, fBK = 64;
constexpr int fMT = cL / fBM, fNT = NROW / fBM;
constexpr int fNBLK = cB * fMT * fNT;

__global__ __launch_bounds__(256) void cph_gemm_fb(
    const float* __restrict__ h, const float* __restrict__ W,
    const float* __restrict__ bias, float* __restrict__ out) {
  __shared__ unsigned short Alds[fBM][fBK];
  __shared__ unsigned short Blds[fBM][fBK];
  int bid = ((int)blockIdx.x & 7) * (fNBLK / 8) + ((int)blockIdx.x >> 3);
  int b   = bid / (fMT * fNT);
  int rem = bid % (fMT * fNT);
  int mt  = rem / fNT, nt = rem % fNT;
  int tid = threadIdx.x, wave = tid >> 6, lane = tid & 63;
  int wm = wave >> 1, wn = wave & 1;
  f32x4 acc[4][4] = {};
  for (int kt = 0; kt < KT; ++kt) {
    __syncthreads();
#pragma unroll
    for (int it = 0; it < 4; ++it) {
      int chunk = tid + it * 256;
      int row = chunk >> 3, c = chunk & 7;
      int pc = c ^ (row & 7);
      const float* asrc = h + ((size_t)b * cL + mt * fBM + row) * cD + kt * fBK + c * 8;
      float4 a0 = *(const float4*)asrc;
      float4 a1 = *(const float4*)(asrc + 4);
      bf16x8 va;
      va[0] = (short)f2bf(a0.x); va[1] = (short)f2bf(a0.y);
      va[2] = (short)f2bf(a0.z); va[3] = (short)f2bf(a0.w);
      va[4] = (short)f2bf(a1.x); va[5] = (short)f2bf(a1.y);
      va[6] = (short)f2bf(a1.z); va[7] = (short)f2bf(a1.w);
      *(bf16x8*)&Alds[row][pc * 8] = va;
      int n = nt * fBM + row;
      int j = n >> 1, o = n & 1;
      const float* bsrc = h + ((size_t)b * cL + j) * cD + kt * fBK + c * 8;
      const float* wsrc = W + (size_t)o * (2 * cD) + kt * fBK + c * 8;
      float4 b0 = *(const float4*)bsrc;
      float4 b1 = *(const float4*)(bsrc + 4);
      float4 w0 = *(const float4*)wsrc;
      float4 w1 = *(const float4*)(wsrc + 4);
      bf16x8 vb;
      vb[0] = (short)f2bf(b0.x * w0.x); vb[1] = (short)f2bf(b0.y * w0.y);
      vb[2] = (short)f2bf(b0.z * w0.z); vb[3] = (short)f2bf(b0.w * w0.w);
      vb[4] = (short)f2bf(b1.x * w1.x); vb[5] = (short)f2bf(b1.y * w1.y);
      vb[6] = (short)f2bf(b1.z * w1.z); vb[7] = (short)f2bf(b1.w * w1.w);
      *(bf16x8*)&Blds[row][pc * 8] = vb;
    }
    __syncthreads();
#pragma unroll
    for (int kk = 0; kk < 2; ++kk) {
      int kc = kk * 4 + (lane >> 4);
      bf16x8 af[4], bfr[4];
#pragma unroll
      for (int m = 0; m < 4; ++m) {
        int r = wm * 64 + m * 16 + (lane & 15);
        af[m] = *(const bf16x8*)&Alds[r][(kc ^ (r & 7)) * 8];
      }
#pragma unroll
      for (int n = 0; n < 4; ++n) {
        int r = wn * 64 + n * 16 + (lane & 15);
        bfr[n] = *(const bf16x8*)&Blds[r][(kc ^ (r & 7)) * 8];
      }
#pragma unroll
      for (int m = 0; m < 4; ++m)
#pragma unroll
        for (int n = 0; n < 4; ++n)
          acc[m][n] = __builtin_amdgcn_mfma_f32_16x16x32_bf16(af[m], bfr[n], acc[m][n], 0, 0, 0);
    }
  }
  int i0 = mt * fBM + wm * 64 + ((lane >> 4) << 2);
  int n0 = nt * fBM + wn * 64 + (lane & 15);
  float badd = bias[n0 & 1];
  float* outb = out + (size_t)b * cL * NROW;
#pragma unroll
  for (int mf = 0; mf < 4; ++mf)
#pragma unroll
    for (int r = 0; r < 4; ++r) {
      size_t rowoff = (size_t)(i0 + mf * 16 + r) * NROW;
#pragma unroll
      for (int nf = 0; nf < 4; ++nf)
        outb[rowoff + n0 + nf * 16] = acc[mf][nf][r] + badd;
    }
}

extern "C" void kernel_launch(void* const* d_in, const int* in_sizes, int n_in,
                              void* d_out, int out_size, void* d_ws, size_t ws_size,
                              hipStream_t stream) {
  const float* h    = (const float*)d_in[0];
  const float* W    = (const float*)d_in[1];
  const float* bias = (const float*)d_in[2];
  float* out        = (float*)d_out;

  size_t a_elems = (size_t)cB * cL * cD;
  size_t b_elems = (size_t)cB * 2 * cL * cD;
  size_t need = (a_elems + b_elems) * sizeof(unsigned short);

  if (ws_size >= need) {
    unsigned short* Apk = (unsigned short*)d_ws;
    unsigned short* Bpk = Apk + a_elems;
    int total_chunks = ACH + BCH;
    cph_pack<<<(total_chunks + 255) / 256, 256, 0, stream>>>(h, W, Apk, Bpk);
    cph_gemm256<<<NPBLK, 512, 0, stream>>>(Apk, Bpk, bias, out);
  } else {
    cph_gemm_fb<<<fNBLK, 256, 0, stream>>>(h, W, bias, out);
  }
}

// Round 13
// 105.162 us; speedup vs baseline: 1.0703x; 1.0703x over previous
//
#include <hip/hip_runtime.h>
#include <hip/hip_bf16.h>

// ContactPredictionHead: logits[b,i,j,o] = sum_d h[b,i,d]*h[b,j,d]*Wp[o,d] + bias[o]
// (diff term antisymmetric -> cancels under symmetrization; prod term symmetric.)
// Batched GEMM: per batch  C[2048 x 4096] = A[2048 x 1280] * Beff^T,
//   Beff[2j+o, d] = h[b,j,d] * Wp[o,d],  row-major C == d_out layout.
// Round 13: REVERT to round-11 (measured optimum: GEMM 84.3-86.8us, 1011 TF,
// MfmaUtil 43.8, bank conflicts 0, total 105.5us). Round 12 proved 32x32
// fragments are structurally conflicted (4-way: 32 rows / 8 chunk columns)
// under global_load_lds's 16B-slab constraint; 16x16 is the only conflict-free
// read shape here. R11 sits on the serialized LDS+MFMA pipe sum
// (~5060 cyc/K-tile); 8 overlap-forcing variants (R5-R12) all failed to beat it.

typedef __attribute__((ext_vector_type(8))) short bf16x8;
typedef __attribute__((ext_vector_type(4))) float f32x4;

constexpr int cB = 4, cL = 2048, cD = 1280, cO = 2;
constexpr int NROW = cL * cO;          // 4096
constexpr int BM = 256, BN = 256, BK = 64;
constexpr int KT = cD / BK;            // 20
constexpr int MT2 = cL / BM;           // 8
constexpr int NT2 = NROW / BN;         // 16
constexpr int NTILE = cB * MT2 * NT2;  // 512 output tiles
constexpr int NPBLK = NTILE / 2;       // 256 persistent blocks

__device__ __forceinline__ unsigned short f2bf(float f) {
  unsigned int u = __float_as_uint(f);
  u += 0x7fffu + ((u >> 16) & 1u);
  return (unsigned short)(u >> 16);
}

#define GLOAD_LDS16(g, l)                                           \
  __builtin_amdgcn_global_load_lds(                                 \
      (const __attribute__((address_space(1))) void*)(g),           \
      (__attribute__((address_space(3))) void*)(l), 16, 0, 0)

// ---------------- pack: h -> bf16 A, (h*Wp) -> bf16 Beff ----------------
constexpr int ACH = cB * cL * cD / 8;
constexpr int BCH = cB * 2 * cL * cD / 8;

__global__ __launch_bounds__(256) void cph_pack(
    const float* __restrict__ h, const float* __restrict__ W,
    unsigned short* __restrict__ Apk, unsigned short* __restrict__ Bpk) {
  int idx = blockIdx.x * 256 + threadIdx.x;
  if (idx < ACH) {
    const float* src = h + (size_t)idx * 8;
    float4 x0 = *(const float4*)src;
    float4 x1 = *(const float4*)(src + 4);
    bf16x8 v;
    v[0] = (short)f2bf(x0.x); v[1] = (short)f2bf(x0.y);
    v[2] = (short)f2bf(x0.z); v[3] = (short)f2bf(x0.w);
    v[4] = (short)f2bf(x1.x); v[5] = (short)f2bf(x1.y);
    v[6] = (short)f2bf(x1.z); v[7] = (short)f2bf(x1.w);
    *(bf16x8*)(Apk + (size_t)idx * 8) = v;
  } else {
    idx -= ACH;
    if (idx >= BCH) return;
    int c = idx % (cD / 8);
    int n = (idx / (cD / 8)) % (2 * cL);
    int b = idx / ((cD / 8) * 2 * cL);
    int j = n >> 1, o = n & 1;
    const float* src = h + ((size_t)b * cL + j) * cD + c * 8;
    const float* ws  = W + (size_t)o * (2 * cD) + c * 8;
    float4 x0 = *(const float4*)src;
    float4 x1 = *(const float4*)(src + 4);
    float4 w0 = *(const float4*)ws;
    float4 w1 = *(const float4*)(ws + 4);
    bf16x8 v;
    v[0] = (short)f2bf(x0.x * w0.x); v[1] = (short)f2bf(x0.y * w0.y);
    v[2] = (short)f2bf(x0.z * w0.z); v[3] = (short)f2bf(x0.w * w0.w);
    v[4] = (short)f2bf(x1.x * w1.x); v[5] = (short)f2bf(x1.y * w1.y);
    v[6] = (short)f2bf(x1.z * w1.z); v[7] = (short)f2bf(x1.w * w1.w);
    *(bf16x8*)(Bpk + ((size_t)b * (2 * cL) + n) * cD + c * 8) = v;
  }
}

// ------------- GEMM: 256x256, 8 waves (2M x 4N), 2 tiles/block -------------
__global__ __launch_bounds__(512, 2) void cph_gemm256(
    const unsigned short* __restrict__ Apk, const unsigned short* __restrict__ Bpk,
    const float* __restrict__ bias, float* __restrict__ out) {
  __shared__ __align__(16) char smem[131072];  // [2 buf][A 32K | B 32K]

  int tid  = threadIdx.x;
  int wave = tid >> 6, lane = tid & 63;
  int wm = wave >> 2, wn = wave & 3;   // per-wave C = 128 x 64

  int lr   = lane >> 3;                 // staging row within an 8-row slab
  int gc8  = ((lane & 7) ^ lr) * 8;     // inverse-swizzled global chunk (elems)
  int l15  = lane & 15;
  int csw0 = (lane >> 4) ^ (lane & 7);  // swizzled 16B-chunk index, kk=0
  int offA0 = wm * 16384 + l15 * 128 + csw0 * 16;
  int offA1 = wm * 16384 + l15 * 128 + (csw0 ^ 4) * 16;
  int offB0 = 32768 + wn * 8192 + l15 * 128 + csw0 * 16;
  int offB1 = 32768 + wn * 8192 + l15 * 128 + (csw0 ^ 4) * 16;
  int dB0 = 32768 + wave * 2048;
  int dB1 = 49152 + wave * 2048;
  int rA0 = ((wave & 4) << 5) + (wave & 3) * 8;   // A slab base row, stripe 0
  int dA0 = rA0 * 128, dA1 = (rA0 + 32) * 128, dA2 = (rA0 + 64) * 128, dA3 = (rA0 + 96) * 128;

  const unsigned short *pB0a, *pB0b, *pB1a, *pB1b, *pA0, *pA1, *pA2, *pA3;
  auto setPtrs = [&](const unsigned short* Ab, const unsigned short* Bb) {
    pB0a = Bb + (size_t)(wave * 16 + lr) * cD + gc8;
    pB0b = pB0a + 8 * (size_t)cD;
    pB1a = Bb + (size_t)(128 + wave * 16 + lr) * cD + gc8;
    pB1b = pB1a + 8 * (size_t)cD;
    pA0 = Ab + (size_t)(rA0 + lr) * cD + gc8;
    pA1 = pA0 + 32 * (size_t)cD;
    pA2 = pA0 + 64 * (size_t)cD;
    pA3 = pA0 + 96 * (size_t)cD;
  };
  auto stageTile = [&](int buf) {
    int bo = buf << 16;
    GLOAD_LDS16(pB0a, smem + bo + dB0);
    GLOAD_LDS16(pB0b, smem + bo + dB0 + 1024);
    GLOAD_LDS16(pB1a, smem + bo + dB1);
    GLOAD_LDS16(pB1b, smem + bo + dB1 + 1024);
    GLOAD_LDS16(pA0, smem + bo + dA0);
    GLOAD_LDS16(pA1, smem + bo + dA1);
    GLOAD_LDS16(pA2, smem + bo + dA2);
    GLOAD_LDS16(pA3, smem + bo + dA3);
    pB0a += BK; pB0b += BK; pB1a += BK; pB1b += BK;
    pA0 += BK; pA1 += BK; pA2 += BK; pA3 += BK;
  };

  f32x4 acc[8][4];

#define MFMA16(base, A, B)                                                    \
  _Pragma("unroll")                                                           \
  for (int m_ = 0; m_ < 4; ++m_)                                              \
    _Pragma("unroll")                                                         \
    for (int nf_ = 0; nf_ < 4; ++nf_)                                         \
      acc[(base) + m_][nf_] = __builtin_amdgcn_mfma_f32_16x16x32_bf16(        \
          A[m_], B[nf_], acc[(base) + m_][nf_], 0, 0, 0);

  // decode tile 0 and prologue-stage it
  {
    int orig = (int)blockIdx.x;
    int bid  = (orig & 7) * (NTILE / 8) + (orig >> 3);
    int b    = bid / (MT2 * NT2);
    int rem  = bid % (MT2 * NT2);
    setPtrs(Apk + ((size_t)b * cL + (rem / NT2) * BM) * cD,
            Bpk + ((size_t)b * NROW + (rem % NT2) * BN) * cD);
  }
  stageTile(0);

#pragma unroll
  for (int part = 0; part < 2; ++part) {
    int orig = (int)blockIdx.x + part * NPBLK;
    int bid  = (orig & 7) * (NTILE / 8) + (orig >> 3);
    int b    = bid / (MT2 * NT2);
    int rem  = bid % (MT2 * NT2);
    int mt   = rem / NT2, nt = rem % NT2;

    asm volatile("s_waitcnt vmcnt(0)");   // this part's tile 0 landed
    __builtin_amdgcn_s_barrier();

#pragma unroll
    for (int mf = 0; mf < 8; ++mf)
#pragma unroll
      for (int nf = 0; nf < 4; ++nf)
        acc[mf][nf] = (f32x4){0.f, 0.f, 0.f, 0.f};

    for (int t = 0; t < KT; ++t) {
      const int X = t & 1;
      const char* bb = smem + (X << 16);
      bf16x8 B0[4], B1[4], Ae[4], Ao[4];

      // critical-path reads FIRST: first cluster's operands enter the
      // LDS FIFO before the 8 stage gloads occupy issue slots
#pragma unroll
      for (int nf = 0; nf < 4; ++nf) B0[nf] = *(const bf16x8*)(bb + offB0 + nf * 2048);
#pragma unroll
      for (int m = 0; m < 4; ++m) Ae[m] = *(const bf16x8*)(bb + offA0 + m * 2048);
#pragma unroll
      for (int m = 0; m < 4; ++m) Ao[m] = *(const bf16x8*)(bb + offA0 + 8192 + m * 2048);

      // then issue next tile's DMA: lands while this tile computes
      if (t + 1 < KT) {
        stageTile(X ^ 1);
      } else if (part == 0) {
        int orig1 = (int)blockIdx.x + NPBLK;
        int bid1  = (orig1 & 7) * (NTILE / 8) + (orig1 >> 3);
        int b1    = bid1 / (MT2 * NT2);
        int rem1  = bid1 % (MT2 * NT2);
        setPtrs(Apk + ((size_t)b1 * cL + (rem1 / NT2) * BM) * cD,
                Bpk + ((size_t)b1 * NROW + (rem1 % NT2) * BN) * cD);
        stageTile(X ^ 1);
      }

      MFMA16(0, Ae, B0);

#pragma unroll
      for (int nf = 0; nf < 4; ++nf) B1[nf] = *(const bf16x8*)(bb + offB1 + nf * 2048);
#pragma unroll
      for (int m = 0; m < 4; ++m) Ae[m] = *(const bf16x8*)(bb + offA1 + m * 2048);
      MFMA16(4, Ao, B0);

#pragma unroll
      for (int m = 0; m < 4; ++m) Ao[m] = *(const bf16x8*)(bb + offA1 + 8192 + m * 2048);
      MFMA16(0, Ae, B1);

      // vmcnt hoisted: next tile's loads were issued ~a full tile ago
      asm volatile("s_waitcnt vmcnt(0)");
      MFMA16(4, Ao, B1);

      if (t + 1 < KT) __builtin_amdgcn_s_barrier();
    }

    // epilogue: C/D 16x16 layout col = lane&15, row = (lane>>4)*4 + reg
    int i0 = mt * BM + wm * 128 + ((lane >> 4) << 2);
    int n0 = nt * BN + wn * 64 + (lane & 15);
    float badd = bias[n0 & 1];
    float* outb = out + (size_t)b * cL * NROW;
#pragma unroll
    for (int mf = 0; mf < 8; ++mf) {
#pragma unroll
      for (int r = 0; r < 4; ++r) {
        size_t rowoff = (size_t)(i0 + mf * 16 + r) * NROW;
#pragma unroll
        for (int nf = 0; nf < 4; ++nf)
          outb[rowoff + n0 + nf * 16] = acc[mf][nf][r] + badd;
      }
    }
  }
#undef MFMA16
}

// ---------------- fallback (ws too small): fused 128^2 full-grid GEMM ----------------
constexpr int fBM = 128, fBK = 64;
constexpr int fMT = cL / fBM, fNT = NROW / fBM;
constexpr int fNBLK = cB * fMT * fNT;

__global__ __launch_bounds__(256) void cph_gemm_fb(
    const float* __restrict__ h, const float* __restrict__ W,
    const float* __restrict__ bias, float* __restrict__ out) {
  __shared__ unsigned short Alds[fBM][fBK];
  __shared__ unsigned short Blds[fBM][fBK];
  int bid = ((int)blockIdx.x & 7) * (fNBLK / 8) + ((int)blockIdx.x >> 3);
  int b   = bid / (fMT * fNT);
  int rem = bid % (fMT * fNT);
  int mt  = rem / fNT, nt = rem % fNT;
  int tid = threadIdx.x, wave = tid >> 6, lane = tid & 63;
  int wm = wave >> 1, wn = wave & 1;
  f32x4 acc[4][4] = {};
  for (int kt = 0; kt < KT; ++kt) {
    __syncthreads();
#pragma unroll
    for (int it = 0; it < 4; ++it) {
      int chunk = tid + it * 256;
      int row = chunk >> 3, c = chunk & 7;
      int pc = c ^ (row & 7);
      const float* asrc = h + ((size_t)b * cL + mt * fBM + row) * cD + kt * fBK + c * 8;
      float4 a0 = *(const float4*)asrc;
      float4 a1 = *(const float4*)(asrc + 4);
      bf16x8 va;
      va[0] = (short)f2bf(a0.x); va[1] = (short)f2bf(a0.y);
      va[2] = (short)f2bf(a0.z); va[3] = (short)f2bf(a0.w);
      va[4] = (short)f2bf(a1.x); va[5] = (short)f2bf(a1.y);
      va[6] = (short)f2bf(a1.z); va[7] = (short)f2bf(a1.w);
      *(bf16x8*)&Alds[row][pc * 8] = va;
      int n = nt * fBM + row;
      int j = n >> 1, o = n & 1;
      const float* bsrc = h + ((size_t)b * cL + j) * cD + kt * fBK + c * 8;
      const float* wsrc = W + (size_t)o * (2 * cD) + kt * fBK + c * 8;
      float4 b0 = *(const float4*)bsrc;
      float4 b1 = *(const float4*)(bsrc + 4);
      float4 w0 = *(const float4*)wsrc;
      float4 w1 = *(const float4*)(wsrc + 4);
      bf16x8 vb;
      vb[0] = (short)f2bf(b0.x * w0.x); vb[1] = (short)f2bf(b0.y * w0.y);
      vb[2] = (short)f2bf(b0.z * w0.z); vb[3] = (short)f2bf(b0.w * w0.w);
      vb[4] = (short)f2bf(b1.x * w1.x); vb[5] = (short)f2bf(b1.y * w1.y);
      vb[6] = (short)f2bf(b1.z * w1.z); vb[7] = (short)f2bf(b1.w * w1.w);
      *(bf16x8*)&Blds[row][pc * 8] = vb;
    }
    __syncthreads();
#pragma unroll
    for (int kk = 0; kk < 2; ++kk) {
      int kc = kk * 4 + (lane >> 4);
      bf16x8 af[4], bfr[4];
#pragma unroll
      for (int m = 0; m < 4; ++m) {
        int r = wm * 64 + m * 16 + (lane & 15);
        af[m] = *(const bf16x8*)&Alds[r][(kc ^ (r & 7)) * 8];
      }
#pragma unroll
      for (int n = 0; n < 4; ++n) {
        int r = wn * 64 + n * 16 + (lane & 15);
        bfr[n] = *(const bf16x8*)&Blds[r][(kc ^ (r & 7)) * 8];
      }
#pragma unroll
      for (int m = 0; m < 4; ++m)
#pragma unroll
        for (int n = 0; n < 4; ++n)
          acc[m][n] = __builtin_amdgcn_mfma_f32_16x16x32_bf16(af[m], bfr[n], acc[m][n], 0, 0, 0);
    }
  }
  int i0 = mt * fBM + wm * 64 + ((lane >> 4) << 2);
  int n0 = nt * fBM + wn * 64 + (lane & 15);
  float badd = bias[n0 & 1];
  float* outb = out + (size_t)b * cL * NROW;
#pragma unroll
  for (int mf = 0; mf < 4; ++mf)
#pragma unroll
    for (int r = 0; r < 4; ++r) {
      size_t rowoff = (size_t)(i0 + mf * 16 + r) * NROW;
#pragma unroll
      for (int nf = 0; nf < 4; ++nf)
        outb[rowoff + n0 + nf * 16] = acc[mf][nf][r] + badd;
    }
}

extern "C" void kernel_launch(void* const* d_in, const int* in_sizes, int n_in,
                              void* d_out, int out_size, void* d_ws, size_t ws_size,
                              hipStream_t stream) {
  const float* h    = (const float*)d_in[0];
  const float* W    = (const float*)d_in[1];
  const float* bias = (const float*)d_in[2];
  float* out        = (float*)d_out;

  size_t a_elems = (size_t)cB * cL * cD;
  size_t b_elems = (size_t)cB * 2 * cL * cD;
  size_t need = (a_elems + b_elems) * sizeof(unsigned short);

  if (ws_size >= need) {
    unsigned short* Apk = (unsigned short*)d_ws;
    unsigned short* Bpk = Apk + a_elems;
    int total_chunks = ACH + BCH;
    cph_pack<<<(total_chunks + 255) / 256, 256, 0, stream>>>(h, W, Apk, Bpk);
    cph_gemm256<<<NPBLK, 512, 0, stream>>>(Apk, Bpk, bias, out);
  } else {
    cph_gemm_fb<<<fNBLK, 256, 0, stream>>>(h, W, bias, out);
  }
}